// Round 2
// baseline (516.265 us; speedup 1.0000x reference)
//
#include <hip/hip_runtime.h>

// LocallyConnected2D: y[n,h,w] = relu(sum_{i,j} x[n,h+i,w+j]*W[h,w,i,j] + b[h,w])
// lane = batch n (N=64=wave) -> weights wave-uniform, sliding window = register reuse.
// R1 lesson: uniform weight pointers got scalarized -> s_load stream -> lgkmcnt(0)
// drains mixed with ds_read = 94% stall. Force weights onto the VMEM path
// (uniform-address vector loads, aligned-float4 windows), fix LDS write conflicts,
// 48 KB LDS -> 3 blocks/CU.

#define H_IN 512
#define W_IN 512
#define H_OUT 504
#define W_OUT 504
#define W_T 8
#define H_T 4
#define TROWS (H_T + 8)   // 12 staged input rows

__launch_bounds__(256, 3)
__global__ void lc2d_kernel(const float* __restrict__ x,
                            const float* __restrict__ weight,
                            const float* __restrict__ bias,
                            float* __restrict__ out) {
    // LDS: [row 0..11][cgrp 0..3][n 0..63][4 floats] = 48 KB
    __shared__ float tile[TROWS * 1024];

    const int t    = threadIdx.x;
    const int lane = t & 63;          // batch index n
    const int wv   = t >> 6;          // wave 0..3

    const int h0 = blockIdx.y * H_T;
    const int w0 = blockIdx.x * W_T;

    // ---- stage x tile: wave wv owns cgrp=wv plane, lane = n ----
    // LDS write: lanes consecutive 16 B -> conflict-free.
    {
        const float* gsrc = x + (size_t)lane * (H_IN * W_IN)
                              + (size_t)h0 * W_IN + w0 + wv * 4;
        float* ldst = &tile[wv * 256 + lane * 4];
        #pragma unroll
        for (int row = 0; row < TROWS; ++row) {
            const float4 v = *reinterpret_cast<const float4*>(gsrc + row * W_IN);
            *reinterpret_cast<float4*>(ldst + row * 1024) = v;
        }
    }
    __syncthreads();

    const int wvu = __builtin_amdgcn_readfirstlane(wv);
    const int h   = h0 + wvu;                         // this wave's output row

    // bias init (tiny, scalar path fine — before the loop)
    float acc[W_T];
    {
        const float* bptr = bias + (size_t)h * W_OUT + w0;
        #pragma unroll
        for (int k = 0; k < W_T; ++k) acc[k] = bptr[k];
    }

    // weight chunk for this wave's 8 outputs: 8*81 floats, 16B-aligned base.
    // vzero: opaque VGPR zero -> compiler cannot scalarize -> global_load (vmcnt).
    int vzero;
    asm volatile("v_mov_b32 %0, 0" : "=v"(vzero));
    const float* wchunk = weight + ((size_t)h * W_OUT + w0) * 81 + vzero;

    #pragma unroll
    for (int r = 0; r < 9; ++r) {
        // x row (wv + r), 16 floats per lane, consecutive-16B ds_read_b128
        float xr[16];
        const int lrow = wv + r;
        #pragma unroll
        for (int c = 0; c < 4; ++c) {
            const float4 v = *reinterpret_cast<const float4*>(
                &tile[lrow * 1024 + c * 256 + lane * 4]);
            xr[4 * c + 0] = v.x; xr[4 * c + 1] = v.y;
            xr[4 * c + 2] = v.z; xr[4 * c + 3] = v.w;
        }
        #pragma unroll
        for (int k = 0; k < W_T; ++k) {
            const int base   = k * 81 + r * 9;   // first tap float of (k, i=r)
            const int astart = base & ~3;        // aligned float4 window start
            const int d      = base & 3;         // compile-time shift
            float f[12];
            #pragma unroll
            for (int q = 0; q < 3; ++q) {
                const float4 v = *reinterpret_cast<const float4*>(wchunk + astart + 4 * q);
                f[4 * q + 0] = v.x; f[4 * q + 1] = v.y;
                f[4 * q + 2] = v.z; f[4 * q + 3] = v.w;
            }
            #pragma unroll
            for (int j = 0; j < 9; ++j)
                acc[k] = fmaf(f[d + j], xr[k + j], acc[k]);
        }
    }

    // ---- epilogue: ReLU + store (1 row x 8 floats per lane, 16B-aligned) ----
    float* o = out + (size_t)lane * (H_OUT * W_OUT) + (size_t)h * W_OUT + w0;
    float4 s;
    s.x = fmaxf(acc[0], 0.f); s.y = fmaxf(acc[1], 0.f);
    s.z = fmaxf(acc[2], 0.f); s.w = fmaxf(acc[3], 0.f);
    *reinterpret_cast<float4*>(o) = s;
    s.x = fmaxf(acc[4], 0.f); s.y = fmaxf(acc[5], 0.f);
    s.z = fmaxf(acc[6], 0.f); s.w = fmaxf(acc[7], 0.f);
    *reinterpret_cast<float4*>(o + 4) = s;
}

extern "C" void kernel_launch(void* const* d_in, const int* in_sizes, int n_in,
                              void* d_out, int out_size, void* d_ws, size_t ws_size,
                              hipStream_t stream) {
    const float* x      = (const float*)d_in[0];
    const float* weight = (const float*)d_in[1];
    const float* bias   = (const float*)d_in[2];
    float* out          = (float*)d_out;

    dim3 grid(W_OUT / W_T, H_OUT / H_T);   // 63 x 126
    dim3 block(256);
    lc2d_kernel<<<grid, block, 0, stream>>>(x, weight, bias, out);
}

// Round 3
// 511.915 us; speedup vs baseline: 1.0085x; 1.0085x over previous
//
#include <hip/hip_runtime.h>

// LocallyConnected2D: y[n,h,w] = relu(sum_{i,j} x[n,h+i,w+j]*W[h,w,i,j] + b[h,w])
// lane = batch n (N=64=wave) -> weights wave-uniform (broadcast), sliding window
// in registers. R1 lesson: uniform weight ptr scalarized -> s_load stream -> stall.
// R2 lesson: float f[12] window array spilled to scratch (WRITE_SIZE 63->223 MB,
// scratch round-trip in dep chain -> 9% VALUBusy). Fix: compile-time float4
// component selection, zero local arrays with variable indices.

#define H_IN 512
#define W_IN 512
#define H_OUT 504
#define W_OUT 504
#define W_T 8
#define H_T 4
#define TROWS (H_T + 8)   // 12 staged input rows

__launch_bounds__(256, 3)
__global__ void lc2d_kernel(const float* __restrict__ x,
                            const float* __restrict__ weight,
                            const float* __restrict__ bias,
                            float* __restrict__ out) {
    // LDS: [row 0..11][cgrp 0..3][n 0..63][4 floats] = 48 KB
    __shared__ float tile[TROWS * 1024];

    const int t    = threadIdx.x;
    const int lane = t & 63;          // batch index n
    const int wv   = t >> 6;          // wave 0..3

    const int h0 = blockIdx.y * H_T;
    const int w0 = blockIdx.x * W_T;

    // ---- stage x tile: wave wv owns cgrp=wv plane, lane = n (conflict-free) ----
    {
        const float* gsrc = x + (size_t)lane * (H_IN * W_IN)
                              + (size_t)h0 * W_IN + w0 + wv * 4;
        float* ldst = &tile[wv * 256 + lane * 4];
        #pragma unroll
        for (int row = 0; row < TROWS; ++row) {
            const float4 v = *reinterpret_cast<const float4*>(gsrc + row * W_IN);
            *reinterpret_cast<float4*>(ldst + row * 1024) = v;
        }
    }
    __syncthreads();

    const int wvu = __builtin_amdgcn_readfirstlane(wv);
    const int h   = h0 + wvu;                         // this wave's output row

    float acc[W_T];
    {
        const float* bptr = bias + (size_t)h * W_OUT + w0;
        #pragma unroll
        for (int k = 0; k < W_T; ++k) acc[k] = bptr[k];
    }

    // weight chunk for this wave's 8 outputs: 648 floats, 16B-aligned base.
    // vzero: opaque VGPR zero -> loads stay on the VMEM (vector) path.
    int vzero;
    asm volatile("v_mov_b32 %0, 0" : "=v"(vzero));
    const float4* wchunk4 =
        reinterpret_cast<const float4*>(weight + ((size_t)h * W_OUT + w0) * 81) + vzero;

    #pragma unroll
    for (int r = 0; r < 9; ++r) {
        // x row (wv + r): 16 floats per lane via 4 conflict-free ds_read_b128
        float xr[16];
        const int lrow = wv + r;
        #pragma unroll
        for (int c = 0; c < 4; ++c) {
            const float4 v = *reinterpret_cast<const float4*>(
                &tile[lrow * 1024 + c * 256 + lane * 4]);
            xr[4 * c + 0] = v.x; xr[4 * c + 1] = v.y;
            xr[4 * c + 2] = v.z; xr[4 * c + 3] = v.w;
        }
        #pragma unroll
        for (int k = 0; k < W_T; ++k) {
            const int base   = k * 81 + r * 9;   // compile-time after unroll
            const int astart = base >> 2;        // aligned float4 index
            const int d      = base & 3;         // compile-time shift
            const float4 v0 = wchunk4[astart + 0];
            const float4 v1 = wchunk4[astart + 1];
            const float4 v2 = wchunk4[astart + 2];
            // 9 taps selected with compile-time components; branches fold away.
            float t0, t1, t2, t3, t4, t5, t6, t7, t8;
            if (d == 0) {
                t0=v0.x; t1=v0.y; t2=v0.z; t3=v0.w; t4=v1.x; t5=v1.y; t6=v1.z; t7=v1.w; t8=v2.x;
            } else if (d == 1) {
                t0=v0.y; t1=v0.z; t2=v0.w; t3=v1.x; t4=v1.y; t5=v1.z; t6=v1.w; t7=v2.x; t8=v2.y;
            } else if (d == 2) {
                t0=v0.z; t1=v0.w; t2=v1.x; t3=v1.y; t4=v1.z; t5=v1.w; t6=v2.x; t7=v2.y; t8=v2.z;
            } else {
                t0=v0.w; t1=v1.x; t2=v1.y; t3=v1.z; t4=v1.w; t5=v2.x; t6=v2.y; t7=v2.z; t8=v2.w;
            }
            acc[k] = fmaf(t0, xr[k + 0], acc[k]);
            acc[k] = fmaf(t1, xr[k + 1], acc[k]);
            acc[k] = fmaf(t2, xr[k + 2], acc[k]);
            acc[k] = fmaf(t3, xr[k + 3], acc[k]);
            acc[k] = fmaf(t4, xr[k + 4], acc[k]);
            acc[k] = fmaf(t5, xr[k + 5], acc[k]);
            acc[k] = fmaf(t6, xr[k + 6], acc[k]);
            acc[k] = fmaf(t7, xr[k + 7], acc[k]);
            acc[k] = fmaf(t8, xr[k + 8], acc[k]);
        }
    }

    // ---- epilogue: ReLU + store (1 row x 8 floats per lane, 16B-aligned) ----
    float* o = out + (size_t)lane * (H_OUT * W_OUT) + (size_t)h * W_OUT + w0;
    float4 s;
    s.x = fmaxf(acc[0], 0.f); s.y = fmaxf(acc[1], 0.f);
    s.z = fmaxf(acc[2], 0.f); s.w = fmaxf(acc[3], 0.f);
    *reinterpret_cast<float4*>(o) = s;
    s.x = fmaxf(acc[4], 0.f); s.y = fmaxf(acc[5], 0.f);
    s.z = fmaxf(acc[6], 0.f); s.w = fmaxf(acc[7], 0.f);
    *reinterpret_cast<float4*>(o + 4) = s;
}

extern "C" void kernel_launch(void* const* d_in, const int* in_sizes, int n_in,
                              void* d_out, int out_size, void* d_ws, size_t ws_size,
                              hipStream_t stream) {
    const float* x      = (const float*)d_in[0];
    const float* weight = (const float*)d_in[1];
    const float* bias   = (const float*)d_in[2];
    float* out          = (float*)d_out;

    dim3 grid(W_OUT / W_T, H_OUT / H_T);   // 63 x 126
    dim3 block(256);
    lc2d_kernel<<<grid, block, 0, stream>>>(x, weight, bias, out);
}

// Round 4
// 388.629 us; speedup vs baseline: 1.3284x; 1.3172x over previous
//
#include <hip/hip_runtime.h>

// LocallyConnected2D: y[n,h,w] = relu(sum_{i,j} x[n,h+i,w+j]*W[h,w,i,j] + b[h,w])
// lane = batch n (N=64=wave). History:
//  R1: weights scalarized (s_load stream) -> lgkmcnt(0) drains -> 354 us.
//  R2: f[12] local array -> scratch spill (WRITE 223 MB) -> 398 us.
//  R3: compile-time selects; spill shrank (191 MB) but uniform global weight
//      loads (216/wave, ~600cyc each) can't be hoisted into 84 VGPRs -> 9% VALUBusy.
//  R4: stage weights in LDS (10.4 KB/block, coalesced float4), compute reads
//      them via wave-uniform ds_read_b128 (broadcast, imm offsets, no VGPR
//      hoisting pressure). x tile staging unchanged (0 conflicts measured).

#define H_IN 512
#define W_IN 512
#define H_OUT 504
#define W_OUT 504
#define W_T 8
#define H_T 4
#define TROWS (H_T + 8)      // 12 staged input rows
#define XF (TROWS * 1024)    // 12288 floats of x tile
#define WF 648               // weight floats per output row chunk (8*81)

__launch_bounds__(256, 2)
__global__ void lc2d_kernel(const float* __restrict__ x,
                            const float* __restrict__ weight,
                            const float* __restrict__ bias,
                            float* __restrict__ out) {
    // LDS: x tile [row 0..11][cgrp 0..3][n 0..63][4] = 48 KB,
    //      then weights [row 0..3][648 floats] = 10.125 KB.  Total 59.5 KB.
    __shared__ float lds[XF + H_T * WF];

    const int t    = threadIdx.x;
    const int lane = t & 63;          // batch index n
    const int wv   = t >> 6;          // wave 0..3

    const int h0 = blockIdx.y * H_T;
    const int w0 = blockIdx.x * W_T;

    // ---- stage x tile (wave wv owns cgrp=wv plane, lane = n; conflict-free) ----
    {
        const float* gsrc = x + (size_t)lane * (H_IN * W_IN)
                              + (size_t)h0 * W_IN + w0 + wv * 4;
        float* ldst = &lds[wv * 256 + lane * 4];
        #pragma unroll
        for (int row = 0; row < TROWS; ++row) {
            const float4 v = *reinterpret_cast<const float4*>(gsrc + row * W_IN);
            *reinterpret_cast<float4*>(ldst + row * 1024) = v;
        }
    }

    // ---- stage weights: 4 rows x 162 float4, fully coalesced ----
    {
        #pragma unroll
        for (int it = 0; it < 3; ++it) {
            const int idx = t + it * 256;          // 0..647 float4 index
            if (idx < H_T * 162) {
                const int row = idx / 162;         // 0..3 (const-div, magic mul)
                const int off = idx - row * 162;   // float4 within row chunk
                const float4 v = *(reinterpret_cast<const float4*>(
                    weight + ((size_t)(h0 + row) * W_OUT + w0) * 81) + off);
                *reinterpret_cast<float4*>(&lds[XF + idx * 4]) = v;
            }
        }
    }
    __syncthreads();

    const int wvu = __builtin_amdgcn_readfirstlane(wv);
    const int h   = h0 + wvu;                      // this wave's output row

    float acc[W_T];
    {
        const float* bptr = bias + (size_t)h * W_OUT + w0;
        #pragma unroll
        for (int k = 0; k < W_T; ++k) acc[k] = bptr[k];
    }

    // this wave's weight chunk in LDS (uniform address -> broadcast reads)
    const float* wlds = &lds[XF + wvu * WF];

    #pragma unroll
    for (int r = 0; r < 9; ++r) {
        // x row (wv + r): 16 floats per lane via 4 conflict-free ds_read_b128
        float xr[16];
        const int lrow = wv + r;
        #pragma unroll
        for (int c = 0; c < 4; ++c) {
            const float4 v = *reinterpret_cast<const float4*>(
                &lds[lrow * 1024 + c * 256 + lane * 4]);
            xr[4 * c + 0] = v.x; xr[4 * c + 1] = v.y;
            xr[4 * c + 2] = v.z; xr[4 * c + 3] = v.w;
        }
        #pragma unroll
        for (int k = 0; k < W_T; ++k) {
            const int base   = k * 81 + r * 9;     // compile-time after unroll
            const int astart = base & ~3;          // aligned float index
            const int d      = base & 3;           // compile-time shift
            const float4 v0 = *reinterpret_cast<const float4*>(wlds + astart);
            const float4 v1 = *reinterpret_cast<const float4*>(wlds + astart + 4);
            const float4 v2 = *reinterpret_cast<const float4*>(wlds + astart + 8);
            float t0, t1, t2, t3, t4, t5, t6, t7, t8;
            if (d == 0) {
                t0=v0.x; t1=v0.y; t2=v0.z; t3=v0.w; t4=v1.x; t5=v1.y; t6=v1.z; t7=v1.w; t8=v2.x;
            } else if (d == 1) {
                t0=v0.y; t1=v0.z; t2=v0.w; t3=v1.x; t4=v1.y; t5=v1.z; t6=v1.w; t7=v2.x; t8=v2.y;
            } else if (d == 2) {
                t0=v0.z; t1=v0.w; t2=v1.x; t3=v1.y; t4=v1.z; t5=v1.w; t6=v2.x; t7=v2.y; t8=v2.z;
            } else {
                t0=v0.w; t1=v1.x; t2=v1.y; t3=v1.z; t4=v1.w; t5=v2.x; t6=v2.y; t7=v2.z; t8=v2.w;
            }
            acc[k] = fmaf(t0, xr[k + 0], acc[k]);
            acc[k] = fmaf(t1, xr[k + 1], acc[k]);
            acc[k] = fmaf(t2, xr[k + 2], acc[k]);
            acc[k] = fmaf(t3, xr[k + 3], acc[k]);
            acc[k] = fmaf(t4, xr[k + 4], acc[k]);
            acc[k] = fmaf(t5, xr[k + 5], acc[k]);
            acc[k] = fmaf(t6, xr[k + 6], acc[k]);
            acc[k] = fmaf(t7, xr[k + 7], acc[k]);
            acc[k] = fmaf(t8, xr[k + 8], acc[k]);
        }
    }

    // ---- epilogue: ReLU + store (1 row x 8 floats per lane, 16B-aligned) ----
    float* o = out + (size_t)lane * (H_OUT * W_OUT) + (size_t)h * W_OUT + w0;
    float4 s;
    s.x = fmaxf(acc[0], 0.f); s.y = fmaxf(acc[1], 0.f);
    s.z = fmaxf(acc[2], 0.f); s.w = fmaxf(acc[3], 0.f);
    *reinterpret_cast<float4*>(o) = s;
    s.x = fmaxf(acc[4], 0.f); s.y = fmaxf(acc[5], 0.f);
    s.z = fmaxf(acc[6], 0.f); s.w = fmaxf(acc[7], 0.f);
    *reinterpret_cast<float4*>(o + 4) = s;
}

extern "C" void kernel_launch(void* const* d_in, const int* in_sizes, int n_in,
                              void* d_out, int out_size, void* d_ws, size_t ws_size,
                              hipStream_t stream) {
    const float* x      = (const float*)d_in[0];
    const float* weight = (const float*)d_in[1];
    const float* bias   = (const float*)d_in[2];
    float* out          = (float*)d_out;

    dim3 grid(W_OUT / W_T, H_OUT / H_T);   // 63 x 126
    dim3 block(256);
    lc2d_kernel<<<grid, block, 0, stream>>>(x, weight, bias, out);
}